// Round 7
// baseline (147.795 us; speedup 1.0000x reference)
//
#include <hip/hip_runtime.h>
#include <math.h>

// Shapes: N=8, Cout=Cin=128, ks=5.
// Output [v(128), o(8), u(128), i(8), 5, 5] fp32, 26,214,400 elems.
// out[v,o,u,i,p,q] = mask[p,q] * bilinear( (1-f)*W[g0,u,v,:,:] + f*W[g1,u,v,:,:],
//                                          rot_o(grid_Rn)[p,q] )
//
// R6 = R5 + block-index swizzle for HBM WRITE page locality.
//   R2/R4/R5 all plateaued at ~49-53 us kernel despite 4x different LDS
//   traffic -> bottleneck is not LDS/VALU. Theory: with vt innermost in bx,
//   ~1500 concurrent blocks write 25.6 KB chunks scattered at 1.6 MB stride
//   over the 105 MB output -> HBM page thrash caps writes at ~2 TB/s (the
//   6.7 TB/s fill streams sequentially). Swizzle ut|o innermost so the
//   resident block cohort writes ~contiguous multi-MB streams per vt.
//   Structure otherwise identical to R5: per-i blended LDS tiles, fixed
//   (i,k) threads, 2x ds_read2 + 4 FMA per output, mask-skip (12/25 zero),
//   coalesced single-owner-line stores from registers.

#define TWO_PI_F 6.28318530717958647692f
#define T_STRIDE 812   // 800 payload words + 12 pad

__global__ __launch_bounds__(256) void rotconv_weight_kernel(
    const float* __restrict__ in_H,    // [8]
    const float* __restrict__ out_H,   // [8]
    const float* __restrict__ weight,  // [8,128,128,5,5]
    const float* __restrict__ grid_Rn, // [2,5,5]
    const float* __restrict__ mask,    // [25]
    float* __restrict__ out)
{
    __shared__ __align__(16) float s_w[8 * T_STRIDE];  // 25,984 B blended tiles
    __shared__ float s_fr[8];
    __shared__ int   s_g0[8], s_g1[8];

    const int t  = threadIdx.x;
    const int bx = blockIdx.x;
    // swizzle: ut innermost (12.8 KB out stride), then o, then vt -> the
    // concurrently-resident cohort shares few vt values => contiguous writes.
    const int ut = bx & 7;
    const int o  = (bx >> 3) & 7;
    const int vt = bx >> 6;          // 0..63
    const int u0 = ut * 16;
    const int v0 = vt * 2;

    const float ang = -out_H[o];

    // ---- per-i rotation-bin params (threads 0..7) ----
    if (t < 8) {
        const float theta = in_H[t] + ang;
        float m = fmodf(theta, TWO_PI_F);
        if (m < 0.0f) m += TWO_PI_F;
        const float pos = m * (8.0f / TWO_PI_F);
        const float pf  = floorf(pos);
        s_fr[t] = pos - pf;
        const int g0 = ((int)pf) & 7;
        s_g0[t] = g0;
        s_g1[t] = (g0 + 1) & 7;
    }
    __syncthreads();

    // ---- phase 1: stage + blend per-i tiles (float2 loads, 8B-aligned) ----
    // tile layout per i: [u(16)][vv(2)][25] = 800 words; 400 float2 per i.
    for (int j = t; j < 3200; j += 256) {
        const int i2 = j / 400;
        const int r  = j - i2 * 400;
        const int u  = r / 25;
        const int e  = r - u * 25;           // float2 index within 50-word run
        const int g0 = s_g0[i2], g1 = s_g1[i2];
        const float fr = s_fr[i2], om = 1.0f - fr;
        const size_t sbase = ((size_t)((u0 + u) * 128) + v0) * 25 + (size_t)e * 2;
        const float2 a = *reinterpret_cast<const float2*>(weight + (size_t)g0 * 409600 + sbase);
        const float2 b = *reinterpret_cast<const float2*>(weight + (size_t)g1 * 409600 + sbase);
        float2 bl;
        bl.x = om * a.x + fr * b.x;
        bl.y = om * a.y + fr * b.y;
        *reinterpret_cast<float2*>(s_w + i2 * T_STRIDE + u * 50 + e * 2) = bl;
    }

    // ---- per-thread fixed (i,k) tap setup (VALU only, overlaps staging) ----
    const int ii = t / 25;                 // 0..7 real; idle tail t>=200
    const int k  = t - ii * 25;
    const int i  = ii > 7 ? 7 : ii;

    float sthe, cthe;
    sincosf(ang, &sthe, &cthe);
    const float X = grid_Rn[k];
    const float Y = grid_Rn[25 + k];
    const float gx = cthe * X - sthe * Y;
    const float gy = sthe * X + cthe * Y;
    const float x = (gx + 1.0f) * 2.0f;    // * 0.5 * (W-1), W=5
    const float y = (gy + 1.0f) * 2.0f;
    const float x0f = floorf(x);
    const float y0f = floorf(y);
    const float fx = x - x0f;              // ref: frac from unclamped floor
    const float fy = y - y0f;
    int x0 = (int)x0f; x0 = x0 < 0 ? 0 : (x0 > 4 ? 4 : x0);
    int y0 = (int)y0f; y0 = y0 < 0 ? 0 : (y0 > 4 ? 4 : y0);
    const int y1 = y0 + 1 > 4 ? 4 : y0 + 1;
    const float mk = mask[k];
    float wa = mk * (1.0f - fy) * (1.0f - fx);
    float wb = mk * (1.0f - fy) * fx;
    float wc = mk * fy * (1.0f - fx);
    float wd = mk * fy * fx;
    int xb = x0;                           // fold x-clamp: taps = (xb, xb+1)
    if (x0 == 4) { xb = 3; wb += wa; wa = 0.0f; wd += wc; wc = 0.0f; }
    const int rb0 = y0 * 5 + xb;
    const int rb1 = y1 * 5 + xb;
    const bool has = (mk != 0.0f);

    __syncthreads();

    if (t >= 200) return;

    // ---- phase 2: 32 runs (uu,vv); reads mask-skipped, stores full-exec ----
    const float* sm = s_w + i * T_STRIDE;
    // out idx: (((v0+vv)*8 + o)*128 + u0+uu)*200 + i*25+k ; i*25+k == t
    const size_t ob0 = (((size_t)v0 * 8 + o) * 128 + u0) * 200 + t;  // vv=0
    const size_t ob1 = ob0 + 204800;                                 // vv=1

    for (int c = 0; c < 4; ++c) {
        float vals[8];
#pragma unroll
        for (int r8 = 0; r8 < 8; ++r8) vals[r8] = 0.0f;
        if (has) {
#pragma unroll
            for (int r8 = 0; r8 < 8; ++r8) {
                const float* tp = sm + (c * 8 + r8) * 25;  // run = c*8+r8
                vals[r8] = wa * tp[rb0] + wb * tp[rb0 + 1]
                         + wc * tp[rb1] + wd * tp[rb1 + 1];
            }
        }
#pragma unroll
        for (int r8 = 0; r8 < 8; ++r8) {
            const int run = c * 8 + r8;
            const int uu  = run >> 1;
            out[((run & 1) ? ob1 : ob0) + (size_t)uu * 200] = vals[r8];
        }
    }
}

extern "C" void kernel_launch(void* const* d_in, const int* in_sizes, int n_in,
                              void* d_out, int out_size, void* d_ws, size_t ws_size,
                              hipStream_t stream) {
    const float* in_H    = (const float*)d_in[0];
    const float* out_H   = (const float*)d_in[1];
    const float* weight  = (const float*)d_in[2];
    // d_in[3] = grid_H (unused)
    const float* grid_Rn = (const float*)d_in[4];
    const float* mask    = (const float*)d_in[5];
    float* out = (float*)d_out;

    // 8 ut x 8 o x 64 vt = 4096 blocks (ut innermost for write locality)
    rotconv_weight_kernel<<<dim3(4096), dim3(256), 0, stream>>>(
        in_H, out_H, weight, grid_Rn, mask, out);
}